// Round 11
// baseline (1514.925 us; speedup 1.0000x reference)
//
#include <hip/hip_runtime.h>

#define NSZ 4096          // NS == NT == 4096
#define DDIM 512
#define NCLS 100
#define EPSF 1e-16f
#define INVN (1.0f/4096.0f)
#define TGT 49152.0f      // e5m2 row-max target (1.5*2^15, exactly representable; max finite 57344)
#define PBLK 256          // persistent kernel blocks (== CU count -> co-residency guaranteed)

typedef unsigned short u16;
typedef unsigned int u32;
typedef __bf16 bf16x8 __attribute__((ext_vector_type(8)));
typedef float floatx4 __attribute__((ext_vector_type(4)));
typedef float floatx2 __attribute__((ext_vector_type(2)));
typedef __attribute__((address_space(1))) void gvoid_t;
typedef __attribute__((address_space(3))) void lvoid_t;

__device__ __forceinline__ float bflo(u32 u) { return __uint_as_float(u << 16); }
__device__ __forceinline__ float bfhi(u32 u) { return __uint_as_float(u & 0xffff0000u); }
__device__ __forceinline__ u32 f2bf(float f) {
  u32 u = __float_as_uint(f);
  return (u + 0x7fffu + ((u >> 16) & 1u)) >> 16;   // RNE
}
__device__ __forceinline__ u32 pk2(float a, float b) { return f2bf(a) | (f2bf(b) << 16); }

__device__ __forceinline__ float wave_sum(float s) {
#pragma unroll
  for (int off = 32; off; off >>= 1) s += __shfl_xor(s, off);
  return s;
}
__device__ __forceinline__ float wave_max(float s) {
#pragma unroll
  for (int off = 32; off; off >>= 1) s = fmaxf(s, __shfl_xor(s, off));
  return s;
}
__device__ __forceinline__ float wave_min(float s) {
#pragma unroll
  for (int off = 32; off; off >>= 1) s = fminf(s, __shfl_xor(s, off));
  return s;
}

// ---- 16B L2-bypass load (sc0 sc1 -> served by LLC, no stale-L2 hazard) ----
__device__ __forceinline__ uint4 bypass_load16(const u32* p) {
  uint4 r;
  asm volatile("global_load_dwordx4 %0, %1, off sc0 sc1\n\ts_waitcnt vmcnt(0)"
               : "=v"(r) : "v"(p) : "memory");
  return r;
}

// ---- cast features to bf16 + row squared-norms (one wave per row) ----
__global__ __launch_bounds__(256) void prep_features(const float* __restrict__ fs, const float* __restrict__ ft,
                                                     u16* __restrict__ fs16, u16* __restrict__ ft16,
                                                     float* __restrict__ nsv, float* __restrict__ ntv) {
  int wid = (blockIdx.x * 256 + threadIdx.x) >> 6;
  int lane = threadIdx.x & 63;
  const float* src; u16* dst; float* nd; int row;
  if (wid < NSZ) { row = wid; src = fs + (size_t)row * DDIM; dst = fs16 + (size_t)row * DDIM; nd = nsv; }
  else           { row = wid - NSZ; src = ft + (size_t)row * DDIM; dst = ft16 + (size_t)row * DDIM; nd = ntv; }
  float4 a = *(const float4*)(src + lane * 8);
  float4 b = *(const float4*)(src + lane * 8 + 4);
  float ss = a.x*a.x + a.y*a.y + a.z*a.z + a.w*a.w + b.x*b.x + b.y*b.y + b.z*b.z + b.w*b.w;
  ss = wave_sum(ss);
  uint4 o;
  o.x = pk2(a.x, a.y); o.y = pk2(a.z, a.w); o.z = pk2(b.x, b.y); o.w = pk2(b.z, b.w);
  *(uint4*)(dst + lane * 8) = o;
  if (lane == 0) nd[row] = ss;
}

// ---- CE table: CEt[c][j] = lse(logits[j]) - logits[j][c]  (one wave per j) ----
__global__ __launch_bounds__(256) void ce_table(const float* __restrict__ logits, float* __restrict__ CEt) {
  int j = blockIdx.x * 4 + (threadIdx.x >> 6);
  int lane = threadIdx.x & 63;
  const float* lr = logits + (size_t)j * NCLS;
  float x0 = lr[lane];
  bool has2 = lane < (NCLS - 64);
  float x1 = has2 ? lr[64 + lane] : -3.4e38f;
  float m = wave_max(fmaxf(x0, x1));
  float s = __expf(x0 - m) + (has2 ? __expf(x1 - m) : 0.f);
  s = wave_sum(s);
  float lse = m + __logf(s);
  CEt[(size_t)lane * NSZ + j] = lse - x0;
  if (has2) CEt[(size_t)(64 + lane) * NSZ + j] = lse - x1;
}

// ---- bf16 MFMA GEMM: g = FS @ FT^T, store g bf16, track max(sq) ----
__global__ __launch_bounds__(256) void gemm_g(const u16* __restrict__ fs16, const u16* __restrict__ ft16,
                                              const float* __restrict__ nsv, const float* __restrict__ ntv,
                                              u16* __restrict__ gbuf, u32* __restrict__ maxbits) {
  __shared__ u16 As[128 * 64];
  __shared__ u16 Bs[128 * 64];
  __shared__ float red[4];
  int t = threadIdx.x;
  int lane = t & 63, w = t >> 6;
  int wr = w >> 1, wc = w & 1;
  int ib = blockIdx.y * 128, jb = blockIdx.x * 128;
  floatx4 acc[4][4] = {};
  for (int k0 = 0; k0 < DDIM; k0 += 64) {
    __syncthreads();
#pragma unroll
    for (int s = 0; s < 4; ++s) {
      int flat = s * 2048 + t * 8;
      int r = flat >> 6, c = flat & 63;
      __builtin_amdgcn_global_load_lds((gvoid_t*)(fs16 + (size_t)(ib + r) * DDIM + k0 + c), (lvoid_t*)&As[flat], 16, 0, 0);
      __builtin_amdgcn_global_load_lds((gvoid_t*)(ft16 + (size_t)(jb + r) * DDIM + k0 + c), (lvoid_t*)&Bs[flat], 16, 0, 0);
    }
    __syncthreads();
#pragma unroll
    for (int kk = 0; kk < 2; ++kk) {
      int ko = kk * 32 + (lane >> 4) * 8;
      bf16x8 af[4], bfv[4];
#pragma unroll
      for (int m = 0; m < 4; ++m) af[m] = *(const bf16x8*)&As[(wr * 64 + m * 16 + (lane & 15)) * 64 + ko];
#pragma unroll
      for (int n = 0; n < 4; ++n) bfv[n] = *(const bf16x8*)&Bs[(wc * 64 + n * 16 + (lane & 15)) * 64 + ko];
#pragma unroll
      for (int m = 0; m < 4; ++m)
#pragma unroll
        for (int n = 0; n < 4; ++n)
          acc[m][n] = __builtin_amdgcn_mfma_f32_16x16x32_bf16(af[m], bfv[n], acc[m][n], 0, 0, 0);
    }
  }
  int rbase = ib + wr * 64, cbase = jb + wc * 64;
  float ntj[4];
#pragma unroll
  for (int n = 0; n < 4; ++n) ntj[n] = ntv[cbase + n * 16 + (lane & 15)];
  float mx = 0.f;
#pragma unroll
  for (int m = 0; m < 4; ++m) {
#pragma unroll
    for (int q = 0; q < 4; ++q) {
      int i = rbase + m * 16 + (lane >> 4) * 4 + q;
      float nsi = nsv[i];
#pragma unroll
      for (int n = 0; n < 4; ++n) {
        float g = acc[m][n][q];
        float sq = nsi + ntj[n] - 2.f * g;
        mx = fmaxf(mx, sq);
        gbuf[(size_t)i * NSZ + cbase + n * 16 + (lane & 15)] = (u16)f2bf(g);
      }
    }
  }
  mx = wave_max(mx);
  if (lane == 0) red[w] = mx;
  __syncthreads();
  if (t == 0) {
    float m4 = fmaxf(fmaxf(red[0], red[1]), fmaxf(red[2], red[3]));
    atomicMax(maxbits, __float_as_uint(m4));   // all values >= 0: uint order == float order
  }
}

__global__ void finish_max(const u32* __restrict__ maxbits, float* __restrict__ invmax) {
  float m = __uint_as_float(*maxbits);
  *invmax = 1.0f / fmaxf(m, EPSF);
}

// ---- fused: per-row min of M + e5m2 encode K~[i][j] = bf8(TGT*exp(-10*(M - rmin_i))) ----
__global__ __launch_bounds__(256) void build_k8(const u16* __restrict__ g, const float* __restrict__ CEt,
                                                const int* __restrict__ labels, const float* __restrict__ nsv,
                                                const float* __restrict__ ntv, const float* __restrict__ invmax,
                                                u32* __restrict__ Km8, float* __restrict__ invs) {
  int i = blockIdx.x, t = threadIdx.x;
  float inv = *invmax;
  float nsi = nsv[i];
  const float* cerow = CEt + (size_t)labels[i] * NSZ;
  const u16* grow = g + (size_t)i * NSZ;
  int j0 = t * 16;
  float mv[16];
  float lmin = 3.4e38f;
#pragma unroll
  for (int h = 0; h < 4; ++h) {
    uint2 gv = *(const uint2*)(grow + j0 + h * 4);      // 4 bf16
    float4 nv = *(const float4*)(ntv + j0 + h * 4);
    float4 cv = *(const float4*)(cerow + j0 + h * 4);
    float m0 = fmaxf(nsi + nv.x - 2.f * bflo(gv.x), 0.f) * inv + cv.x;
    float m1 = fmaxf(nsi + nv.y - 2.f * bfhi(gv.x), 0.f) * inv + cv.y;
    float m2 = fmaxf(nsi + nv.z - 2.f * bflo(gv.y), 0.f) * inv + cv.z;
    float m3 = fmaxf(nsi + nv.w - 2.f * bfhi(gv.y), 0.f) * inv + cv.w;
    mv[h * 4 + 0] = m0; mv[h * 4 + 1] = m1; mv[h * 4 + 2] = m2; mv[h * 4 + 3] = m3;
    lmin = fminf(lmin, fminf(fminf(m0, m1), fminf(m2, m3)));
  }
  lmin = wave_min(lmin);
  __shared__ float red[4];
  if ((t & 63) == 0) red[t >> 6] = lmin;
  __syncthreads();
  float rmin = fminf(fminf(red[0], red[1]), fminf(red[2], red[3]));
  if (t == 0) invs[i] = __expf(-10.f * rmin) / TGT;
  u32 wds[4];
#pragma unroll
  for (int q = 0; q < 4; ++q) {
    float z0 = TGT * __expf(-10.f * (mv[q * 4 + 0] - rmin));
    float z1 = TGT * __expf(-10.f * (mv[q * 4 + 1] - rmin));
    float z2 = TGT * __expf(-10.f * (mv[q * 4 + 2] - rmin));
    float z3 = TGT * __expf(-10.f * (mv[q * 4 + 3] - rmin));
    int wd = 0;
    wd = __builtin_amdgcn_cvt_pk_bf8_f32(z0, z1, wd, false);
    wd = __builtin_amdgcn_cvt_pk_bf8_f32(z2, z3, wd, true);
    wds[q] = (u32)wd;
  }
  uint4 o = { wds[0], wds[1], wds[2], wds[3] };
  *(uint4*)(Km8 + (size_t)i * (NSZ / 4) + t * 4) = o;
}

// ---- out-of-place byte transpose of 4096x4096 fp8, 128x128-byte tiles ----
__global__ __launch_bounds__(256) void transpose8(const u32* __restrict__ A, u32* __restrict__ B) {
  int bi = blockIdx.y, bj = blockIdx.x;
  __shared__ u32 ta[128][33];
  int t = threadIdx.x;
  int r0 = t >> 5, w = t & 31;
  size_t base_a = (size_t)(bi * 128) * 1024 + bj * 32;   // word index; row stride 1024 words
  size_t base_b = (size_t)(bj * 128) * 1024 + bi * 32;
#pragma unroll
  for (int p = 0; p < 16; ++p) {
    int r = r0 + p * 8;
    ta[r][w] = A[base_a + (size_t)r * 1024 + w];
  }
  __syncthreads();
#pragma unroll
  for (int p = 0; p < 16; ++p) {
    int c = r0 + p * 8;
    int cw = c >> 2, cs = (c & 3) * 8;
    u32 o = ((ta[4 * w + 0][cw] >> cs) & 0xffu)
          | (((ta[4 * w + 1][cw] >> cs) & 0xffu) << 8)
          | (((ta[4 * w + 2][cw] >> cs) & 0xffu) << 16)
          | (((ta[4 * w + 3][cw] >> cs) & 0xffu) << 24);
    B[base_b + (size_t)c * 1024 + w] = o;
  }
}

// ---- e5m2 row dot: K row in REGISTERS, x in LDS, packed-FP32 FMA ----
__device__ __forceinline__ float dot_reg(const u32* __restrict__ kreg, const float* __restrict__ xs, int lane) {
  floatx2 acc0 = { 0.f, 0.f }, acc1 = { 0.f, 0.f };
#pragma unroll
  for (int c = 0; c < 16; ++c) {
    u32 kw = kreg[c];                                   // cols c*256 + 4*lane .. +3
    float4 xv = *(const float4*)&xs[c * 256 + lane * 4];
    floatx2 xlo = { xv.x, xv.y }, xhi = { xv.z, xv.w };
    floatx2 p0 = __builtin_amdgcn_cvt_pk_f32_bf8(kw, false);
    floatx2 p1 = __builtin_amdgcn_cvt_pk_f32_bf8(kw, true);
    asm("v_pk_fma_f32 %0, %1, %2, %0" : "+v"(acc0) : "v"(p0), "v"(xlo));
    asm("v_pk_fma_f32 %0, %1, %2, %0" : "+v"(acc1) : "v"(p1), "v"(xhi));
  }
  return wave_sum((acc0.x + acc0.y) + (acc1.x + acc1.y));
}

// ---- stage one 16B slice with cached-first + bypass-fallback readiness ----
__device__ __forceinline__ float4 stage16(const float* __restrict__ base, int tid) {
  float4 xv = ((const float4*)base)[tid];               // plain cached load
  if (!(xv.x > 0.f && xv.y > 0.f && xv.z > 0.f && xv.w > 0.f)) {
    const u32* bsrc = (const u32*)base + tid * 4;
    uint4 r;
    for (;;) {
      r = bypass_load16(bsrc);
      if (r.x && r.y && r.z && r.w) break;
      __builtin_amdgcn_s_sleep(3);                      // backoff: cut LLC spin pressure
    }
    xv = *(float4*)&r;
  }
  return xv;
}

// ---- persistent Sinkhorn v7: dataflow sync + cached-first staging + dbuf LDS ----
// Double-buffered xs -> ONE __syncthreads per phase (the pre-dot one). xs[0] reuse at
// it+1 is ordered by: sync_mid(it) happens-after all u-dots(it); v-dot(it) is after
// sync_mid(it); staging xs[0](it+1) is after v-dot(it) in program order.
__global__ __launch_bounds__(1024, 4) void sinkhorn_persist7(
    const u32* __restrict__ Km8, const u32* __restrict__ KT8,
    const float* __restrict__ invs, float* __restrict__ ubuf,
    float* __restrict__ vbuf) {
  __shared__ float xs0[NSZ];                            // u-phase buffer (16 KB)
  __shared__ float xs1[NSZ];                            // v-phase buffer (16 KB)
  int tid = threadIdx.x;
  int w = tid >> 6, lane = tid & 63;
  int row = blockIdx.x * 16 + w;                        // one row per wave, 4096 total
  // load this wave's K~ row and K~T row into registers: 16+16 dwords/lane (4 KB/row)
  u32 ka[16], kb[16];
#pragma unroll
  for (int c = 0; c < 16; ++c) {
    ka[c] = Km8[(size_t)row * (NSZ / 4) + c * 64 + lane];
    kb[c] = KT8[(size_t)row * (NSZ / 4) + c * 64 + lane];
  }
  float iv = invs[row];
  for (int it = 0; it < 100; ++it) {
    // ---- u-phase: stage v_it into xs0, dot K~ row, bypass-store uhat
    if (it == 0) {
      float4 iv4 = { INVN, INVN, INVN, INVN };
      ((float4*)xs0)[tid] = iv4;
    } else {
      ((float4*)xs0)[tid] = stage16(vbuf + (size_t)it * NSZ, tid);
    }
    __syncthreads();                                    // xs0 complete (also: xs1 of it-1 consumed)
    float s = dot_reg(ka, xs0, lane);
    if (lane == 0)
      __hip_atomic_store(&ubuf[(size_t)it * NSZ + row],
                         fmaxf(iv * (INVN / fmaxf(iv * s, EPSF)), 1e-35f),
                         __ATOMIC_RELAXED, __HIP_MEMORY_SCOPE_AGENT);
    // ---- v-phase: stage uhat_it into xs1 (issues immediately after this wave's dot)
    ((float4*)xs1)[tid] = stage16(ubuf + (size_t)it * NSZ, tid);
    __syncthreads();                                    // xs1 complete (also: xs0 consumed by all)
    float z = dot_reg(kb, xs1, lane);
    if (lane == 0)
      __hip_atomic_store(&vbuf[(size_t)(it + 1) * NSZ + row],
                         fmaxf(INVN / fmaxf(z, EPSF), 1e-35f),
                         __ATOMIC_RELAXED, __HIP_MEMORY_SCOPE_AGENT);
  }
}

// ---- loss partials: sum_ij uhat_i * dec8(K~_ij) * v_j * M_ij, M recomputed from g ----
__global__ __launch_bounds__(256) void loss_partial8(const u16* __restrict__ g, const u32* __restrict__ Km8,
                                                     const float* __restrict__ CEt, const int* __restrict__ labels,
                                                     const float* __restrict__ nsv, const float* __restrict__ ntv,
                                                     const float* __restrict__ invmax, const float* __restrict__ uhat,
                                                     const float* __restrict__ vv, float* __restrict__ partials) {
  int lane = threadIdx.x & 63, w = threadIdx.x >> 6;
  int row = blockIdx.x * 4 + w;
  float inv = *invmax;
  float nsi = nsv[row];
  const float* cerow = CEt + (size_t)labels[row] * NSZ;
  const u16* grow = g + (size_t)row * NSZ;
  const u32* krow = Km8 + (size_t)row * (NSZ / 4);
  float s = 0.f;
  for (int c = 0; c < NSZ; c += 512) {
    int j = c + lane * 8;
    uint4 gv = *(const uint4*)(grow + j);
    uint2 kv = *(const uint2*)(krow + (j >> 2));
    float4 na = *(const float4*)(ntv + j);
    float4 nb = *(const float4*)(ntv + j + 4);
    float4 ca = *(const float4*)(cerow + j);
    float4 cb = *(const float4*)(cerow + j + 4);
    float4 va = *(const float4*)(vv + j);
    float4 vb = *(const float4*)(vv + j + 4);
    float gg[8] = { bflo(gv.x), bfhi(gv.x), bflo(gv.y), bfhi(gv.y),
                    bflo(gv.z), bfhi(gv.z), bflo(gv.w), bfhi(gv.w) };
    float nt8[8] = { na.x, na.y, na.z, na.w, nb.x, nb.y, nb.z, nb.w };
    float ce8[8] = { ca.x, ca.y, ca.z, ca.w, cb.x, cb.y, cb.z, cb.w };
    float vv8[8] = { va.x, va.y, va.z, va.w, vb.x, vb.y, vb.z, vb.w };
    float z8[8];
    floatx2 p;
    p = __builtin_amdgcn_cvt_pk_f32_bf8(kv.x, false); z8[0] = p.x; z8[1] = p.y;
    p = __builtin_amdgcn_cvt_pk_f32_bf8(kv.x, true ); z8[2] = p.x; z8[3] = p.y;
    p = __builtin_amdgcn_cvt_pk_f32_bf8(kv.y, false); z8[4] = p.x; z8[5] = p.y;
    p = __builtin_amdgcn_cvt_pk_f32_bf8(kv.y, true ); z8[6] = p.x; z8[7] = p.y;
#pragma unroll
    for (int k = 0; k < 8; ++k) {
      float m = fmaxf(nsi + nt8[k] - 2.f * gg[k], 0.f) * inv + ce8[k];
      s += z8[k] * vv8[k] * m;
    }
  }
  s = wave_sum(s);
  __shared__ float red[4];
  if (lane == 0) red[w] = uhat[row] * s;
  __syncthreads();
  if (threadIdx.x == 0) partials[blockIdx.x] = red[0] + red[1] + red[2] + red[3];
}

__global__ __launch_bounds__(256) void loss_final(const float* __restrict__ partials, float* __restrict__ out) {
  int t = threadIdx.x;
  float s = partials[t] + partials[t + 256] + partials[t + 512] + partials[t + 768];
  s = wave_sum(s);
  __shared__ float red[4];
  if ((t & 63) == 0) red[t >> 6] = s;
  __syncthreads();
  if (t == 0) out[0] = red[0] + red[1] + red[2] + red[3];
}

extern "C" void kernel_launch(void* const* d_in, const int* in_sizes, int n_in,
                              void* d_out, int out_size, void* d_ws, size_t ws_size,
                              hipStream_t stream) {
  const int* labels = (const int*)d_in[0];
  const float* logits = (const float*)d_in[1];
  const float* fs = (const float*)d_in[2];
  const float* ft = (const float*)d_in[3];
  float* out = (float*)d_out;

  // workspace carve (~69 MB; fs16/ft16 alias Km8 region — disjoint lifetimes)
  char* w = (char*)d_ws;
  auto carve = [&](size_t b) { char* p = w; w += (b + 255) & ~(size_t)255; return p; };
  u16* gbuf = (u16*)carve((size_t)NSZ * NSZ * 2);       // 32 MB, live until loss
  u32* Km8 = (u32*)carve((size_t)NSZ * NSZ);            // 16 MB e5m2 (row-scaled)
  u32* KT8 = (u32*)carve((size_t)NSZ * NSZ);            // 16 MB e5m2 transpose
  float* CEt = (float*)carve((size_t)NCLS * NSZ * 4);   // 1.6 MB
  float* nsv = (float*)carve(NSZ * 4);
  float* ntv = (float*)carve(NSZ * 4);
  float* ubuf = (float*)carve((size_t)100 * NSZ * 4);   // 1.6 MB iteration-indexed uhat (write-once slots)
  float* vbuf = (float*)carve((size_t)101 * NSZ * 4);   // 1.65 MB iteration-indexed v   (write-once slots)
  float* invs = (float*)carve(NSZ * 4);
  u32* maxbits = (u32*)carve(256);
  float* invmax = (float*)carve(256);
  float* partials = (float*)carve(1024 * 4);
  // aliases (dead after gemm_g, before build_k8 writes Km8):
  u16* fs16 = (u16*)Km8;
  u16* ft16 = (u16*)Km8 + (size_t)NSZ * DDIM;

  hipMemsetAsync(maxbits, 0, 4, stream);
  // zero == "not yet written" sentinel for dataflow sync; re-zeroed every call (graph-safe)
  hipMemsetAsync(ubuf, 0, (size_t)(100 + 101) * NSZ * 4 + 256, stream);
  prep_features<<<2048, 256, 0, stream>>>(fs, ft, fs16, ft16, nsv, ntv);
  ce_table<<<1024, 256, 0, stream>>>(logits, CEt);
  gemm_g<<<dim3(32, 32), 256, 0, stream>>>(fs16, ft16, nsv, ntv, gbuf, maxbits);
  finish_max<<<1, 1, 0, stream>>>(maxbits, invmax);
  build_k8<<<4096, 256, 0, stream>>>(gbuf, CEt, labels, nsv, ntv, invmax, Km8, invs);
  transpose8<<<dim3(32, 32), 256, 0, stream>>>(Km8, KT8);
  sinkhorn_persist7<<<PBLK, 1024, 0, stream>>>(Km8, KT8, invs, ubuf, vbuf);
  loss_partial8<<<1024, 256, 0, stream>>>(gbuf, Km8, CEt, labels, nsv, ntv, invmax,
                                          ubuf + (size_t)99 * NSZ, vbuf + (size_t)100 * NSZ, partials);
  loss_final<<<1, 256, 0, stream>>>(partials, out);
}

// Round 12
// 581.431 us; speedup vs baseline: 2.6055x; 2.6055x over previous
//
#include <hip/hip_runtime.h>

#define NSZ 4096          // NS == NT == 4096
#define DDIM 512
#define NCLS 100
#define EPSF 1e-16f
#define INVN (1.0f/4096.0f)
#define TGT 49152.0f      // e5m2 row-max target (1.5*2^15, exactly representable; max finite 57344)
#define PBLK 256          // persistent kernel blocks (== CU count -> co-residency guaranteed)

typedef unsigned short u16;
typedef unsigned int u32;
typedef __bf16 bf16x8 __attribute__((ext_vector_type(8)));
typedef float floatx4 __attribute__((ext_vector_type(4)));
typedef float floatx2 __attribute__((ext_vector_type(2)));
typedef __attribute__((address_space(1))) void gvoid_t;
typedef __attribute__((address_space(3))) void lvoid_t;

__device__ __forceinline__ float bflo(u32 u) { return __uint_as_float(u << 16); }
__device__ __forceinline__ float bfhi(u32 u) { return __uint_as_float(u & 0xffff0000u); }
__device__ __forceinline__ u32 f2bf(float f) {
  u32 u = __float_as_uint(f);
  return (u + 0x7fffu + ((u >> 16) & 1u)) >> 16;   // RNE
}
__device__ __forceinline__ u32 pk2(float a, float b) { return f2bf(a) | (f2bf(b) << 16); }

__device__ __forceinline__ float wave_sum(float s) {
#pragma unroll
  for (int off = 32; off; off >>= 1) s += __shfl_xor(s, off);
  return s;
}
__device__ __forceinline__ float wave_max(float s) {
#pragma unroll
  for (int off = 32; off; off >>= 1) s = fmaxf(s, __shfl_xor(s, off));
  return s;
}
__device__ __forceinline__ float wave_min(float s) {
#pragma unroll
  for (int off = 32; off; off >>= 1) s = fminf(s, __shfl_xor(s, off));
  return s;
}

// ---- 16B L2-bypass load (sc0 sc1 -> served by LLC, no stale-L2 hazard) ----
__device__ __forceinline__ uint4 bypass_load16(const u32* p) {
  uint4 r;
  asm volatile("global_load_dwordx4 %0, %1, off sc0 sc1\n\ts_waitcnt vmcnt(0)"
               : "=v"(r) : "v"(p) : "memory");
  return r;
}

// ---- cast features to bf16 + row squared-norms (one wave per row) ----
__global__ __launch_bounds__(256) void prep_features(const float* __restrict__ fs, const float* __restrict__ ft,
                                                     u16* __restrict__ fs16, u16* __restrict__ ft16,
                                                     float* __restrict__ nsv, float* __restrict__ ntv) {
  int wid = (blockIdx.x * 256 + threadIdx.x) >> 6;
  int lane = threadIdx.x & 63;
  const float* src; u16* dst; float* nd; int row;
  if (wid < NSZ) { row = wid; src = fs + (size_t)row * DDIM; dst = fs16 + (size_t)row * DDIM; nd = nsv; }
  else           { row = wid - NSZ; src = ft + (size_t)row * DDIM; dst = ft16 + (size_t)row * DDIM; nd = ntv; }
  float4 a = *(const float4*)(src + lane * 8);
  float4 b = *(const float4*)(src + lane * 8 + 4);
  float ss = a.x*a.x + a.y*a.y + a.z*a.z + a.w*a.w + b.x*b.x + b.y*b.y + b.z*b.z + b.w*b.w;
  ss = wave_sum(ss);
  uint4 o;
  o.x = pk2(a.x, a.y); o.y = pk2(a.z, a.w); o.z = pk2(b.x, b.y); o.w = pk2(b.z, b.w);
  *(uint4*)(dst + lane * 8) = o;
  if (lane == 0) nd[row] = ss;
}

// ---- CE table: CEt[c][j] = lse(logits[j]) - logits[j][c]  (one wave per j) ----
__global__ __launch_bounds__(256) void ce_table(const float* __restrict__ logits, float* __restrict__ CEt) {
  int j = blockIdx.x * 4 + (threadIdx.x >> 6);
  int lane = threadIdx.x & 63;
  const float* lr = logits + (size_t)j * NCLS;
  float x0 = lr[lane];
  bool has2 = lane < (NCLS - 64);
  float x1 = has2 ? lr[64 + lane] : -3.4e38f;
  float m = wave_max(fmaxf(x0, x1));
  float s = __expf(x0 - m) + (has2 ? __expf(x1 - m) : 0.f);
  s = wave_sum(s);
  float lse = m + __logf(s);
  CEt[(size_t)lane * NSZ + j] = lse - x0;
  if (has2) CEt[(size_t)(64 + lane) * NSZ + j] = lse - x1;
}

// ---- bf16 MFMA GEMM: g = FS @ FT^T, store g bf16, track max(sq) ----
__global__ __launch_bounds__(256) void gemm_g(const u16* __restrict__ fs16, const u16* __restrict__ ft16,
                                              const float* __restrict__ nsv, const float* __restrict__ ntv,
                                              u16* __restrict__ gbuf, u32* __restrict__ maxbits) {
  __shared__ u16 As[128 * 64];
  __shared__ u16 Bs[128 * 64];
  __shared__ float red[4];
  int t = threadIdx.x;
  int lane = t & 63, w = t >> 6;
  int wr = w >> 1, wc = w & 1;
  int ib = blockIdx.y * 128, jb = blockIdx.x * 128;
  floatx4 acc[4][4] = {};
  for (int k0 = 0; k0 < DDIM; k0 += 64) {
    __syncthreads();
#pragma unroll
    for (int s = 0; s < 4; ++s) {
      int flat = s * 2048 + t * 8;
      int r = flat >> 6, c = flat & 63;
      __builtin_amdgcn_global_load_lds((gvoid_t*)(fs16 + (size_t)(ib + r) * DDIM + k0 + c), (lvoid_t*)&As[flat], 16, 0, 0);
      __builtin_amdgcn_global_load_lds((gvoid_t*)(ft16 + (size_t)(jb + r) * DDIM + k0 + c), (lvoid_t*)&Bs[flat], 16, 0, 0);
    }
    __syncthreads();
#pragma unroll
    for (int kk = 0; kk < 2; ++kk) {
      int ko = kk * 32 + (lane >> 4) * 8;
      bf16x8 af[4], bfv[4];
#pragma unroll
      for (int m = 0; m < 4; ++m) af[m] = *(const bf16x8*)&As[(wr * 64 + m * 16 + (lane & 15)) * 64 + ko];
#pragma unroll
      for (int n = 0; n < 4; ++n) bfv[n] = *(const bf16x8*)&Bs[(wc * 64 + n * 16 + (lane & 15)) * 64 + ko];
#pragma unroll
      for (int m = 0; m < 4; ++m)
#pragma unroll
        for (int n = 0; n < 4; ++n)
          acc[m][n] = __builtin_amdgcn_mfma_f32_16x16x32_bf16(af[m], bfv[n], acc[m][n], 0, 0, 0);
    }
  }
  int rbase = ib + wr * 64, cbase = jb + wc * 64;
  float ntj[4];
#pragma unroll
  for (int n = 0; n < 4; ++n) ntj[n] = ntv[cbase + n * 16 + (lane & 15)];
  float mx = 0.f;
#pragma unroll
  for (int m = 0; m < 4; ++m) {
#pragma unroll
    for (int q = 0; q < 4; ++q) {
      int i = rbase + m * 16 + (lane >> 4) * 4 + q;
      float nsi = nsv[i];
#pragma unroll
      for (int n = 0; n < 4; ++n) {
        float g = acc[m][n][q];
        float sq = nsi + ntj[n] - 2.f * g;
        mx = fmaxf(mx, sq);
        gbuf[(size_t)i * NSZ + cbase + n * 16 + (lane & 15)] = (u16)f2bf(g);
      }
    }
  }
  mx = wave_max(mx);
  if (lane == 0) red[w] = mx;
  __syncthreads();
  if (t == 0) {
    float m4 = fmaxf(fmaxf(red[0], red[1]), fmaxf(red[2], red[3]));
    atomicMax(maxbits, __float_as_uint(m4));   // all values >= 0: uint order == float order
  }
}

__global__ void finish_max(const u32* __restrict__ maxbits, float* __restrict__ invmax) {
  float m = __uint_as_float(*maxbits);
  *invmax = 1.0f / fmaxf(m, EPSF);
}

// ---- fused: per-row min of M + e5m2 encode K~[i][j] = bf8(TGT*exp(-10*(M - rmin_i))) ----
__global__ __launch_bounds__(256) void build_k8(const u16* __restrict__ g, const float* __restrict__ CEt,
                                                const int* __restrict__ labels, const float* __restrict__ nsv,
                                                const float* __restrict__ ntv, const float* __restrict__ invmax,
                                                u32* __restrict__ Km8, float* __restrict__ invs) {
  int i = blockIdx.x, t = threadIdx.x;
  float inv = *invmax;
  float nsi = nsv[i];
  const float* cerow = CEt + (size_t)labels[i] * NSZ;
  const u16* grow = g + (size_t)i * NSZ;
  int j0 = t * 16;
  float mv[16];
  float lmin = 3.4e38f;
#pragma unroll
  for (int h = 0; h < 4; ++h) {
    uint2 gv = *(const uint2*)(grow + j0 + h * 4);      // 4 bf16
    float4 nv = *(const float4*)(ntv + j0 + h * 4);
    float4 cv = *(const float4*)(cerow + j0 + h * 4);
    float m0 = fmaxf(nsi + nv.x - 2.f * bflo(gv.x), 0.f) * inv + cv.x;
    float m1 = fmaxf(nsi + nv.y - 2.f * bfhi(gv.x), 0.f) * inv + cv.y;
    float m2 = fmaxf(nsi + nv.z - 2.f * bflo(gv.y), 0.f) * inv + cv.z;
    float m3 = fmaxf(nsi + nv.w - 2.f * bfhi(gv.y), 0.f) * inv + cv.w;
    mv[h * 4 + 0] = m0; mv[h * 4 + 1] = m1; mv[h * 4 + 2] = m2; mv[h * 4 + 3] = m3;
    lmin = fminf(lmin, fminf(fminf(m0, m1), fminf(m2, m3)));
  }
  lmin = wave_min(lmin);
  __shared__ float red[4];
  if ((t & 63) == 0) red[t >> 6] = lmin;
  __syncthreads();
  float rmin = fminf(fminf(red[0], red[1]), fminf(red[2], red[3]));
  if (t == 0) invs[i] = __expf(-10.f * rmin) / TGT;
  u32 wds[4];
#pragma unroll
  for (int q = 0; q < 4; ++q) {
    float z0 = TGT * __expf(-10.f * (mv[q * 4 + 0] - rmin));
    float z1 = TGT * __expf(-10.f * (mv[q * 4 + 1] - rmin));
    float z2 = TGT * __expf(-10.f * (mv[q * 4 + 2] - rmin));
    float z3 = TGT * __expf(-10.f * (mv[q * 4 + 3] - rmin));
    int wd = 0;
    wd = __builtin_amdgcn_cvt_pk_bf8_f32(z0, z1, wd, false);
    wd = __builtin_amdgcn_cvt_pk_bf8_f32(z2, z3, wd, true);
    wds[q] = (u32)wd;
  }
  uint4 o = { wds[0], wds[1], wds[2], wds[3] };
  *(uint4*)(Km8 + (size_t)i * (NSZ / 4) + t * 4) = o;
}

// ---- out-of-place byte transpose of 4096x4096 fp8, 128x128-byte tiles ----
__global__ __launch_bounds__(256) void transpose8(const u32* __restrict__ A, u32* __restrict__ B) {
  int bi = blockIdx.y, bj = blockIdx.x;
  __shared__ u32 ta[128][33];
  int t = threadIdx.x;
  int r0 = t >> 5, w = t & 31;
  size_t base_a = (size_t)(bi * 128) * 1024 + bj * 32;   // word index; row stride 1024 words
  size_t base_b = (size_t)(bj * 128) * 1024 + bi * 32;
#pragma unroll
  for (int p = 0; p < 16; ++p) {
    int r = r0 + p * 8;
    ta[r][w] = A[base_a + (size_t)r * 1024 + w];
  }
  __syncthreads();
#pragma unroll
  for (int p = 0; p < 16; ++p) {
    int c = r0 + p * 8;
    int cw = c >> 2, cs = (c & 3) * 8;
    u32 o = ((ta[4 * w + 0][cw] >> cs) & 0xffu)
          | (((ta[4 * w + 1][cw] >> cs) & 0xffu) << 8)
          | (((ta[4 * w + 2][cw] >> cs) & 0xffu) << 16)
          | (((ta[4 * w + 3][cw] >> cs) & 0xffu) << 24);
    B[base_b + (size_t)c * 1024 + w] = o;
  }
}

// ---- e5m2 row dot: K row in REGISTERS, x in LDS, packed-FP32 FMA ----
__device__ __forceinline__ float dot_reg(const u32* __restrict__ kreg, const float* __restrict__ xs, int lane) {
  floatx2 acc0 = { 0.f, 0.f }, acc1 = { 0.f, 0.f };
#pragma unroll
  for (int c = 0; c < 16; ++c) {
    u32 kw = kreg[c];                                   // cols c*256 + 4*lane .. +3
    float4 xv = *(const float4*)&xs[c * 256 + lane * 4];
    floatx2 xlo = { xv.x, xv.y }, xhi = { xv.z, xv.w };
    floatx2 p0 = __builtin_amdgcn_cvt_pk_f32_bf8(kw, false);
    floatx2 p1 = __builtin_amdgcn_cvt_pk_f32_bf8(kw, true);
    asm("v_pk_fma_f32 %0, %1, %2, %0" : "+v"(acc0) : "v"(p0), "v"(xlo));
    asm("v_pk_fma_f32 %0, %1, %2, %0" : "+v"(acc1) : "v"(p1), "v"(xhi));
  }
  return wave_sum((acc0.x + acc0.y) + (acc1.x + acc1.y));
}

// ---- publish one scalar: authoritative bypass store (LLC) + volatile cached store
// (plants the valid line in the producer XCD's L2 so same-XCD cached-first reads hit) ----
__device__ __forceinline__ void publish(float* addr, float val) {
  __hip_atomic_store(addr, val, __ATOMIC_RELAXED, __HIP_MEMORY_SCOPE_AGENT);  // LLC first
  *(volatile float*)addr = val;                                               // local L2 copy
}

// ---- persistent Sinkhorn v8 (= proven v6 structure + producer L2 publish) ----
// Write-once, strictly-positive slots in zero-initialized iteration-indexed buffers:
// value > 0 == ready. Stage tries a PLAIN CACHED 16B load first (post-dot sync aligns
// consumers after producers — the v11 lesson: that sync is a throttle, keep it);
// fallback is the authoritative L2-bypass spin.
__global__ __launch_bounds__(1024, 4) void sinkhorn_persist8(
    const u32* __restrict__ Km8, const u32* __restrict__ KT8,
    const float* __restrict__ invs, float* __restrict__ ubuf,
    float* __restrict__ vbuf) {
  __shared__ float xs[NSZ];                             // 16 KB staged x per block
  int tid = threadIdx.x;
  int w = tid >> 6, lane = tid & 63;
  int row = blockIdx.x * 16 + w;                        // one row per wave, 4096 total
  // load this wave's K~ row and K~T row into registers: 16+16 dwords/lane (4 KB/row)
  u32 ka[16], kb[16];
#pragma unroll
  for (int c = 0; c < 16; ++c) {
    ka[c] = Km8[(size_t)row * (NSZ / 4) + c * 64 + lane];
    kb[c] = KT8[(size_t)row * (NSZ / 4) + c * 64 + lane];
  }
  float iv = invs[row];
  float4* xs4 = (float4*)xs;
  for (int it = 0; it < 100; ++it) {
    // ---- u-phase: stage v_it (cached-first, bypass fallback), dot K~ row
    if (it == 0) {
      float4 iv4 = { INVN, INVN, INVN, INVN };
      xs4[tid] = iv4;
    } else {
      const float* base = vbuf + (size_t)it * NSZ;
      float4 xv = ((const float4*)base)[tid];           // plain cached load
      if (!(xv.x > 0.f && xv.y > 0.f && xv.z > 0.f && xv.w > 0.f)) {
        const u32* bsrc = (const u32*)base + tid * 4;
        uint4 r;
        for (;;) {
          r = bypass_load16(bsrc);
          if (r.x && r.y && r.z && r.w) break;
          __builtin_amdgcn_s_sleep(1);
        }
        xv = *(float4*)&r;
      }
      xs4[tid] = xv;
    }
    __syncthreads();
    float s = dot_reg(ka, xs, lane);
    if (lane == 0)
      publish(&ubuf[(size_t)it * NSZ + row],
              fmaxf(iv * (INVN / fmaxf(iv * s, EPSF)), 1e-35f));
    __syncthreads();                                    // throttle: consumers read after producers
    // ---- v-phase: stage uhat_it (cached-first, bypass fallback), dot K~T row
    {
      const float* base = ubuf + (size_t)it * NSZ;
      float4 xv = ((const float4*)base)[tid];           // plain cached load
      if (!(xv.x > 0.f && xv.y > 0.f && xv.z > 0.f && xv.w > 0.f)) {
        const u32* bsrc = (const u32*)base + tid * 4;
        uint4 r;
        for (;;) {
          r = bypass_load16(bsrc);
          if (r.x && r.y && r.z && r.w) break;
          __builtin_amdgcn_s_sleep(1);
        }
        xv = *(float4*)&r;
      }
      xs4[tid] = xv;
    }
    __syncthreads();
    float z = dot_reg(kb, xs, lane);
    if (lane == 0)
      publish(&vbuf[(size_t)(it + 1) * NSZ + row],
              fmaxf(INVN / fmaxf(z, EPSF), 1e-35f));
    __syncthreads();                                    // throttle: consumers read after producers
  }
}

// ---- loss partials: sum_ij uhat_i * dec8(K~_ij) * v_j * M_ij, M recomputed from g ----
__global__ __launch_bounds__(256) void loss_partial8(const u16* __restrict__ g, const u32* __restrict__ Km8,
                                                     const float* __restrict__ CEt, const int* __restrict__ labels,
                                                     const float* __restrict__ nsv, const float* __restrict__ ntv,
                                                     const float* __restrict__ invmax, const float* __restrict__ uhat,
                                                     const float* __restrict__ vv, float* __restrict__ partials) {
  int lane = threadIdx.x & 63, w = threadIdx.x >> 6;
  int row = blockIdx.x * 4 + w;
  float inv = *invmax;
  float nsi = nsv[row];
  const float* cerow = CEt + (size_t)labels[row] * NSZ;
  const u16* grow = g + (size_t)row * NSZ;
  const u32* krow = Km8 + (size_t)row * (NSZ / 4);
  float s = 0.f;
  for (int c = 0; c < NSZ; c += 512) {
    int j = c + lane * 8;
    uint4 gv = *(const uint4*)(grow + j);
    uint2 kv = *(const uint2*)(krow + (j >> 2));
    float4 na = *(const float4*)(ntv + j);
    float4 nb = *(const float4*)(ntv + j + 4);
    float4 ca = *(const float4*)(cerow + j);
    float4 cb = *(const float4*)(cerow + j + 4);
    float4 va = *(const float4*)(vv + j);
    float4 vb = *(const float4*)(vv + j + 4);
    float gg[8] = { bflo(gv.x), bfhi(gv.x), bflo(gv.y), bfhi(gv.y),
                    bflo(gv.z), bfhi(gv.z), bflo(gv.w), bfhi(gv.w) };
    float nt8[8] = { na.x, na.y, na.z, na.w, nb.x, nb.y, nb.z, nb.w };
    float ce8[8] = { ca.x, ca.y, ca.z, ca.w, cb.x, cb.y, cb.z, cb.w };
    float vv8[8] = { va.x, va.y, va.z, va.w, vb.x, vb.y, vb.z, vb.w };
    float z8[8];
    floatx2 p;
    p = __builtin_amdgcn_cvt_pk_f32_bf8(kv.x, false); z8[0] = p.x; z8[1] = p.y;
    p = __builtin_amdgcn_cvt_pk_f32_bf8(kv.x, true ); z8[2] = p.x; z8[3] = p.y;
    p = __builtin_amdgcn_cvt_pk_f32_bf8(kv.y, false); z8[4] = p.x; z8[5] = p.y;
    p = __builtin_amdgcn_cvt_pk_f32_bf8(kv.y, true ); z8[6] = p.x; z8[7] = p.y;
#pragma unroll
    for (int k = 0; k < 8; ++k) {
      float m = fmaxf(nsi + nt8[k] - 2.f * gg[k], 0.f) * inv + ce8[k];
      s += z8[k] * vv8[k] * m;
    }
  }
  s = wave_sum(s);
  __shared__ float red[4];
  if (lane == 0) red[w] = uhat[row] * s;
  __syncthreads();
  if (threadIdx.x == 0) partials[blockIdx.x] = red[0] + red[1] + red[2] + red[3];
}

__global__ __launch_bounds__(256) void loss_final(const float* __restrict__ partials, float* __restrict__ out) {
  int t = threadIdx.x;
  float s = partials[t] + partials[t + 256] + partials[t + 512] + partials[t + 768];
  s = wave_sum(s);
  __shared__ float red[4];
  if ((t & 63) == 0) red[t >> 6] = s;
  __syncthreads();
  if (t == 0) out[0] = red[0] + red[1] + red[2] + red[3];
}

extern "C" void kernel_launch(void* const* d_in, const int* in_sizes, int n_in,
                              void* d_out, int out_size, void* d_ws, size_t ws_size,
                              hipStream_t stream) {
  const int* labels = (const int*)d_in[0];
  const float* logits = (const float*)d_in[1];
  const float* fs = (const float*)d_in[2];
  const float* ft = (const float*)d_in[3];
  float* out = (float*)d_out;

  // workspace carve (~69 MB; fs16/ft16 alias Km8 region — disjoint lifetimes)
  char* w = (char*)d_ws;
  auto carve = [&](size_t b) { char* p = w; w += (b + 255) & ~(size_t)255; return p; };
  u16* gbuf = (u16*)carve((size_t)NSZ * NSZ * 2);       // 32 MB, live until loss
  u32* Km8 = (u32*)carve((size_t)NSZ * NSZ);            // 16 MB e5m2 (row-scaled)
  u32* KT8 = (u32*)carve((size_t)NSZ * NSZ);            // 16 MB e5m2 transpose
  float* CEt = (float*)carve((size_t)NCLS * NSZ * 4);   // 1.6 MB
  float* nsv = (float*)carve(NSZ * 4);
  float* ntv = (float*)carve(NSZ * 4);
  float* ubuf = (float*)carve((size_t)100 * NSZ * 4);   // 1.6 MB iteration-indexed uhat (write-once slots)
  float* vbuf = (float*)carve((size_t)101 * NSZ * 4);   // 1.65 MB iteration-indexed v   (write-once slots)
  float* invs = (float*)carve(NSZ * 4);
  u32* maxbits = (u32*)carve(256);
  float* invmax = (float*)carve(256);
  float* partials = (float*)carve(1024 * 4);
  // aliases (dead after gemm_g, before build_k8 writes Km8):
  u16* fs16 = (u16*)Km8;
  u16* ft16 = (u16*)Km8 + (size_t)NSZ * DDIM;

  hipMemsetAsync(maxbits, 0, 4, stream);
  // zero == "not yet written" sentinel for dataflow sync; re-zeroed every call (graph-safe)
  hipMemsetAsync(ubuf, 0, (size_t)(100 + 101) * NSZ * 4 + 256, stream);
  prep_features<<<2048, 256, 0, stream>>>(fs, ft, fs16, ft16, nsv, ntv);
  ce_table<<<1024, 256, 0, stream>>>(logits, CEt);
  gemm_g<<<dim3(32, 32), 256, 0, stream>>>(fs16, ft16, nsv, ntv, gbuf, maxbits);
  finish_max<<<1, 1, 0, stream>>>(maxbits, invmax);
  build_k8<<<4096, 256, 0, stream>>>(gbuf, CEt, labels, nsv, ntv, invmax, Km8, invs);
  transpose8<<<dim3(32, 32), 256, 0, stream>>>(Km8, KT8);
  sinkhorn_persist8<<<PBLK, 1024, 0, stream>>>(Km8, KT8, invs, ubuf, vbuf);
  loss_partial8<<<1024, 256, 0, stream>>>(gbuf, Km8, CEt, labels, nsv, ntv, invmax,
                                          ubuf + (size_t)99 * NSZ, vbuf + (size_t)100 * NSZ, partials);
  loss_final<<<1, 256, 0, stream>>>(partials, out);
}